// Round 14
// baseline (26.506 us; speedup 1.0000x reference)
//
#include <hip/hip_runtime.h>

#define NPIX (384*384)        // 147456
#define NSAMP 32
#define ROWS 64               // 32 region rows + 32 affinity rows
#define BINS2 2048            // exponent(8) + 4 mantissa bits; l in [0,1) -> bin <= 2031
#define REPL 2                // LDS histogram replication
#define THREADS 256
#define BLKROW 32             // chunks per sample; fused grid = 32 x 32 = 1024 blocks
#define EPB (NPIX / BLKROW)   // 4608 elements per block = 4 full + 1 half iter
#define SELTHREADS 1024

// workspace layout (no zero-init needed anywhere):
//   part [ROWS][BLKROW][BINS2/2] u32  (two u16 counts packed; 8 MB, plain stores)
//   pstat[ROWS][BLKROW]          u64  per-block (n_pos<<32 | f32bits(pos_sum))
// per-block count <= 4608 < 2^16 fits u16.
#define PART_U32   ((size_t)ROWS * BLKROW * (BINS2 / 2))
#define PSTAT_OFF  (PART_U32 * 4)

// Fused per (samp, chunk) block: loads the 5 arrays ONCE for its 4608 pixels
// and builds BOTH region and affinity 2048-bin count histograms in LDS
// (u32, 2-way replicated; 32 KB). Cuts logical reads 113->94 MB (conf was
// read twice in the split version). ZERO global atomics (R9 lesson).
__global__ __launch_bounds__(THREADS, 4) void k_hist(
    const float* __restrict__ gt_r, const float* __restrict__ gt_a,
    const float* __restrict__ pr_r, const float* __restrict__ pr_a,
    const float* __restrict__ conf,
    unsigned int* __restrict__ part,
    unsigned long long* __restrict__ pstat,
    float* __restrict__ out)
{
    __shared__ unsigned int s_cnt[2 * BINS2 * REPL];   // 32 KB: [type][bin][copy]
    __shared__ unsigned int s_pc[2];
    __shared__ float s_ps[2];
    const int tid = threadIdx.x;
    const int samp = blockIdx.y;
    const int chunk = blockIdx.x;
    const unsigned copy = tid & (REPL - 1);

    // zero d_out for k_sel's atomicAdd (safe: consumed only after this kernel)
    if (samp == 0 && chunk == 0 && tid == 0) out[0] = 0.f;

    for (int i = tid; i < 2 * BINS2 * REPL; i += THREADS) s_cnt[i] = 0u;
    if (tid < 2) { s_pc[tid] = 0u; s_ps[tid] = 0.f; }
    __syncthreads();

    const size_t base0 = (size_t)samp * NPIX + (size_t)chunk * EPB;
    unsigned pc_r = 0, pc_a = 0; float ps_r = 0.f, ps_a = 0.f;

    #pragma unroll
    for (int it = 0; it < 5; ++it) {            // it==4 is the half-iteration
        if (it == 4 && tid >= 128) break;
        size_t idx = base0 + (size_t)it * THREADS * 4 + (size_t)tid * 4;
        float4 gr = *(const float4*)(gt_r + idx);
        float4 prr = *(const float4*)(pr_r + idx);
        float4 ga = *(const float4*)(gt_a + idx);
        float4 pa = *(const float4*)(pr_a + idx);
        float4 cf = *(const float4*)(conf + idx);
        float grv[4] = {gr.x, gr.y, gr.z, gr.w};
        float prv[4] = {prr.x, prr.y, prr.z, prr.w};
        float gav[4] = {ga.x, ga.y, ga.z, ga.w};
        float pav[4] = {pa.x, pa.y, pa.z, pa.w};
        float cfv[4] = {cf.x, cf.y, cf.z, cf.w};
        #pragma unroll
        for (int j = 0; j < 4; ++j) {
            float c = cfv[j];
            float dr = prv[j] - grv[j];
            float lr = dr * dr * c;
            if (grv[j] >= 0.1f) { pc_r++; ps_r += lr; }
            else {
                unsigned bin = __float_as_uint(lr) >> 19;   // lr < 1 -> bin <= 2031
                atomicAdd(&s_cnt[(bin << 1) | copy], 1u);
            }
            float da = pav[j] - gav[j];
            float la = da * da * c;
            if (gav[j] >= 0.1f) { pc_a++; ps_a += la; }
            else {
                unsigned bin = __float_as_uint(la) >> 19;
                atomicAdd(&s_cnt[(1 << 12) | (bin << 1) | copy], 1u);
            }
        }
    }

    // wave-reduce positive stats -> LDS (no global atomics)
    for (int off = 32; off; off >>= 1) {
        pc_r += __shfl_down(pc_r, off); ps_r += __shfl_down(ps_r, off);
        pc_a += __shfl_down(pc_a, off); ps_a += __shfl_down(ps_a, off);
    }
    if ((tid & 63) == 0) {
        atomicAdd(&s_pc[0], pc_r); atomicAdd(&s_ps[0], ps_r);
        atomicAdd(&s_pc[1], pc_a); atomicAdd(&s_ps[1], ps_a);
    }
    __syncthreads();

    // private flush: pack counts of bins (2w, 2w+1) into one u32, plain stores
    #pragma unroll
    for (int t = 0; t < 2; ++t) {
        const int row = samp + t * NSAMP;
        unsigned int* dst = part + ((size_t)row * BLKROW + chunk) * (BINS2 / 2);
        const unsigned int* src = s_cnt + (t << 12);
        for (int w = tid; w < BINS2 / 2; w += THREADS) {
            unsigned lo = src[(w << 2) | 0] + src[(w << 2) | 1];   // cnt(2w)
            unsigned hi = src[(w << 2) | 2] + src[(w << 2) | 3];   // cnt(2w+1)
            dst[w] = lo | (hi << 16);
        }
    }
    if (tid < 2)
        pstat[(size_t)(samp + tid * NSAMP) * BLKROW + chunk] =
            ((unsigned long long)s_pc[tid] << 32) |
            (unsigned long long)__float_as_uint(s_ps[tid]);
}

// Geometric center of histogram bin b (bins are [lo, lo*(1+1/32)) slices).
__device__ __forceinline__ float bin_center(int b)
{
    return __uint_as_float(((unsigned)b) << 19) * 1.015625f;
}

// Per row, 1024 threads (2 descending ranks/thread): reduce 32 stat pairs,
// sum 32 packed partials (one u32/thread/chunk), two-level inclusive scan,
// boundary bin's partial take approximated by bin_center.
__global__ __launch_bounds__(SELTHREADS) void k_sel(
    const unsigned int* __restrict__ part,
    const unsigned long long* __restrict__ pstat,
    float* __restrict__ out)
{
    const int row = blockIdx.x;           // 0..63
    const int tid = threadIdx.x;          // 0..1023
    __shared__ unsigned s_npos; __shared__ float s_psum;
    __shared__ unsigned wtc[16]; __shared__ float wts[16];

    // wave 0 reduces the 32 per-block stat pairs
    if (tid < 64) {
        unsigned pc = 0; float ps = 0.f;
        if (tid < BLKROW) {
            unsigned long long v = pstat[(size_t)row * BLKROW + tid];
            pc = (unsigned)(v >> 32);
            ps = __uint_as_float((unsigned)(v & 0xFFFFFFFFu));
        }
        for (int off = 32; off; off >>= 1) {
            pc += __shfl_down(pc, off);
            ps += __shfl_down(ps, off);
        }
        if (tid == 0) { s_npos = pc; s_psum = ps; }
    }

    // thread t owns ranks (2t, 2t+1) -> bins (2047-2t, 2046-2t), both inside
    // packed word wi = 1023 - t: hi16 = cnt(2047-2t), lo16 = cnt(2046-2t).
    const unsigned int* base = part + (size_t)row * BLKROW * (BINS2 / 2)
                             + (BINS2 / 2 - 1 - tid);
    unsigned c0 = 0, c1 = 0;
    #pragma unroll
    for (int ch = 0; ch < BLKROW; ++ch) {
        unsigned v = base[(size_t)ch * (BINS2 / 2)];
        c0 += v >> 16;          // rank 2t   (bin 2047-2t)
        c1 += v & 0xFFFFu;      // rank 2t+1 (bin 2046-2t)
    }
    const int bin0 = BINS2 - 1 - 2 * tid;
    const int bin1 = bin0 - 1;
    float s0 = (float)c0 * bin_center(bin0);
    float s1 = (float)c1 * bin_center(bin1);
    unsigned tc = c0 + c1; float ts = s0 + s1;

    // two-level inclusive scan over (tc, ts) in rank order (16 waves)
    unsigned lane = tid & 63, w = tid >> 6;
    unsigned ic = tc; float is = ts;
    #pragma unroll
    for (int off = 1; off < 64; off <<= 1) {
        unsigned uc = __shfl_up(ic, off);
        float    us = __shfl_up(is, off);
        if (lane >= off) { ic += uc; is += us; }
    }
    if (lane == 63) { wtc[w] = ic; wts[w] = is; }
    __syncthreads();
    unsigned woc = 0; float wos = 0.f;
    for (unsigned i = 0; i < w; ++i) { woc += wtc[i]; wos += wts[i]; }
    unsigned before_c = woc + ic - tc;   // count strictly above my first rank
    float    before_s = wos + is - ts;

    const unsigned n_pos = s_npos;
    const float pos_sum = s_psum;
    const unsigned n_neg = NPIX - n_pos;
    const float pos_part = (n_pos > 0u) ? pos_sum / (float)n_pos : 0.f;
    if (n_neg == 0u) {
        if (tid == 0) atomicAdd(out, (pos_part - 1.f) / (float)NSAMP); // sentinel -1
        return;
    }
    unsigned k;
    if (n_pos > 0u) {
        k = 3u * n_pos;
        if (k > n_neg) k = n_neg;
        if (k < 1u) k = 1u;
    } else {
        k = 500u;   // fallback: top-500 (all pixels are negatives when n_pos==0)
    }

    if (before_c < k && before_c + c0 >= k) {
        unsigned kpp = k - before_c;
        float topk = before_s + (float)kpp * bin_center(bin0);
        atomicAdd(out, (pos_part + topk / (float)k) / (float)NSAMP);
    }
    before_c += c0; before_s += s0;
    if (before_c < k && before_c + c1 >= k) {
        unsigned kpp = k - before_c;
        float topk = before_s + (float)kpp * bin_center(bin1);
        atomicAdd(out, (pos_part + topk / (float)k) / (float)NSAMP);
    }
}

extern "C" void kernel_launch(void* const* d_in, const int* in_sizes, int n_in,
                              void* d_out, int out_size, void* d_ws, size_t ws_size,
                              hipStream_t stream)
{
    (void)in_sizes; (void)n_in; (void)out_size; (void)ws_size;
    const float* gt_r = (const float*)d_in[0];
    const float* gt_a = (const float*)d_in[1];
    const float* pr_r = (const float*)d_in[2];
    const float* pr_a = (const float*)d_in[3];
    const float* conf = (const float*)d_in[4];

    char* ws = (char*)d_ws;
    unsigned int*       part  = (unsigned int*)ws;
    unsigned long long* pstat = (unsigned long long*)(ws + PSTAT_OFF);

    dim3 gridH(BLKROW, NSAMP);
    k_hist<<<gridH, THREADS, 0, stream>>>(gt_r, gt_a, pr_r, pr_a, conf,
                                          part, pstat, (float*)d_out);
    k_sel<<<ROWS, SELTHREADS, 0, stream>>>(part, pstat, (float*)d_out);
}

// Round 15
// 25.917 us; speedup vs baseline: 1.0227x; 1.0227x over previous
//
#include <hip/hip_runtime.h>

#define NPIX (384*384)        // 147456
#define NSAMP 32
#define ROWS 64               // 32 region rows + 32 affinity rows
#define BINS2 2048            // exponent(8) + 4 mantissa bits; l in [0,1) -> bin <= 2031
#define REPL 2                // LDS histogram replication
#define THREADS 512           // fused blocks: 1024 x 512 = 524288 = exact machine fill
#define BLKROW 32             // chunks per sample
#define EPB (NPIX / BLKROW)   // 4608 elements per block = 2 full + 1 quarter iter
#define SELTHREADS 1024

// workspace layout (no zero-init needed anywhere):
//   part [ROWS][BLKROW][BINS2/2] u32  (two u16 counts packed; 8 MB, plain stores)
//   pstat[ROWS][BLKROW]          u64  per-block (n_pos<<32 | f32bits(pos_sum))
// per-block count <= 4608 < 2^16 fits u16.
#define PART_U32   ((size_t)ROWS * BLKROW * (BINS2 / 2))
#define PSTAT_OFF  (PART_U32 * 4)

// Fused per (samp, chunk) block, 512 threads: loads the 5 arrays ONCE for its
// 4608 pixels, builds BOTH region and affinity 2048-bin count histograms in
// LDS (u32, 2-way replicated; 32 KB). vs R13-split: -17% logical reads at
// IDENTICAL wave occupancy (32 waves/CU) and per-thread atomic chain (18).
// ZERO global atomics (R9 lesson).
__global__ __launch_bounds__(THREADS, 8) void k_hist(
    const float* __restrict__ gt_r, const float* __restrict__ gt_a,
    const float* __restrict__ pr_r, const float* __restrict__ pr_a,
    const float* __restrict__ conf,
    unsigned int* __restrict__ part,
    unsigned long long* __restrict__ pstat,
    float* __restrict__ out)
{
    __shared__ unsigned int s_cnt[2 * BINS2 * REPL];   // 32 KB: [type][bin][copy]
    __shared__ unsigned int s_pc[2];
    __shared__ float s_ps[2];
    const int tid = threadIdx.x;          // 0..511
    const int samp = blockIdx.y;
    const int chunk = blockIdx.x;
    const unsigned copy = tid & (REPL - 1);

    // zero d_out for k_sel's atomicAdd (safe: consumed only after this kernel)
    if (samp == 0 && chunk == 0 && tid == 0) out[0] = 0.f;

    for (int i = tid; i < 2 * BINS2 * REPL; i += THREADS) s_cnt[i] = 0u;
    if (tid < 2) { s_pc[tid] = 0u; s_ps[tid] = 0.f; }
    __syncthreads();

    const size_t base0 = (size_t)samp * NPIX + (size_t)chunk * EPB;
    unsigned pc_r = 0, pc_a = 0; float ps_r = 0.f, ps_a = 0.f;

    #pragma unroll
    for (int it = 0; it < 3; ++it) {            // it==2 is the quarter-iteration
        if (it == 2 && tid >= 128) break;       // 4608 = 2*2048 + 512
        size_t idx = base0 + (size_t)it * THREADS * 4 + (size_t)tid * 4;
        float4 gr = *(const float4*)(gt_r + idx);
        float4 prr = *(const float4*)(pr_r + idx);
        float4 ga = *(const float4*)(gt_a + idx);
        float4 pa = *(const float4*)(pr_a + idx);
        float4 cf = *(const float4*)(conf + idx);
        float grv[4] = {gr.x, gr.y, gr.z, gr.w};
        float prv[4] = {prr.x, prr.y, prr.z, prr.w};
        float gav[4] = {ga.x, ga.y, ga.z, ga.w};
        float pav[4] = {pa.x, pa.y, pa.z, pa.w};
        float cfv[4] = {cf.x, cf.y, cf.z, cf.w};
        #pragma unroll
        for (int j = 0; j < 4; ++j) {
            float c = cfv[j];
            float dr = prv[j] - grv[j];
            float lr = dr * dr * c;
            if (grv[j] >= 0.1f) { pc_r++; ps_r += lr; }
            else {
                unsigned bin = __float_as_uint(lr) >> 19;   // lr < 1 -> bin <= 2031
                atomicAdd(&s_cnt[(bin << 1) | copy], 1u);
            }
            float da = pav[j] - gav[j];
            float la = da * da * c;
            if (gav[j] >= 0.1f) { pc_a++; ps_a += la; }
            else {
                unsigned bin = __float_as_uint(la) >> 19;
                atomicAdd(&s_cnt[(1 << 12) | (bin << 1) | copy], 1u);
            }
        }
    }

    // wave-reduce positive stats -> LDS (no global atomics)
    for (int off = 32; off; off >>= 1) {
        pc_r += __shfl_down(pc_r, off); ps_r += __shfl_down(ps_r, off);
        pc_a += __shfl_down(pc_a, off); ps_a += __shfl_down(ps_a, off);
    }
    if ((tid & 63) == 0) {
        atomicAdd(&s_pc[0], pc_r); atomicAdd(&s_ps[0], ps_r);
        atomicAdd(&s_pc[1], pc_a); atomicAdd(&s_ps[1], ps_a);
    }
    __syncthreads();

    // private flush: pack counts of bins (2w, 2w+1) into one u32, plain stores
    #pragma unroll
    for (int t = 0; t < 2; ++t) {
        const int row = samp + t * NSAMP;
        unsigned int* dst = part + ((size_t)row * BLKROW + chunk) * (BINS2 / 2);
        const unsigned int* src = s_cnt + (t << 12);
        for (int w = tid; w < BINS2 / 2; w += THREADS) {
            unsigned lo = src[(w << 2) | 0] + src[(w << 2) | 1];   // cnt(2w)
            unsigned hi = src[(w << 2) | 2] + src[(w << 2) | 3];   // cnt(2w+1)
            dst[w] = lo | (hi << 16);
        }
    }
    if (tid < 2)
        pstat[(size_t)(samp + tid * NSAMP) * BLKROW + chunk] =
            ((unsigned long long)s_pc[tid] << 32) |
            (unsigned long long)__float_as_uint(s_ps[tid]);
}

// Geometric center of histogram bin b (bins are [lo, lo*(1+1/32)) slices).
__device__ __forceinline__ float bin_center(int b)
{
    return __uint_as_float(((unsigned)b) << 19) * 1.015625f;
}

// Per row, 1024 threads (2 descending ranks/thread): reduce 32 stat pairs,
// sum 32 packed partials (one u32/thread/chunk), two-level inclusive scan,
// boundary bin's partial take approximated by bin_center.
__global__ __launch_bounds__(SELTHREADS) void k_sel(
    const unsigned int* __restrict__ part,
    const unsigned long long* __restrict__ pstat,
    float* __restrict__ out)
{
    const int row = blockIdx.x;           // 0..63
    const int tid = threadIdx.x;          // 0..1023
    __shared__ unsigned s_npos; __shared__ float s_psum;
    __shared__ unsigned wtc[16]; __shared__ float wts[16];

    // wave 0 reduces the 32 per-block stat pairs
    if (tid < 64) {
        unsigned pc = 0; float ps = 0.f;
        if (tid < BLKROW) {
            unsigned long long v = pstat[(size_t)row * BLKROW + tid];
            pc = (unsigned)(v >> 32);
            ps = __uint_as_float((unsigned)(v & 0xFFFFFFFFu));
        }
        for (int off = 32; off; off >>= 1) {
            pc += __shfl_down(pc, off);
            ps += __shfl_down(ps, off);
        }
        if (tid == 0) { s_npos = pc; s_psum = ps; }
    }

    // thread t owns ranks (2t, 2t+1) -> bins (2047-2t, 2046-2t), both inside
    // packed word wi = 1023 - t: hi16 = cnt(2047-2t), lo16 = cnt(2046-2t).
    const unsigned int* base = part + (size_t)row * BLKROW * (BINS2 / 2)
                             + (BINS2 / 2 - 1 - tid);
    unsigned c0 = 0, c1 = 0;
    #pragma unroll
    for (int ch = 0; ch < BLKROW; ++ch) {
        unsigned v = base[(size_t)ch * (BINS2 / 2)];
        c0 += v >> 16;          // rank 2t   (bin 2047-2t)
        c1 += v & 0xFFFFu;      // rank 2t+1 (bin 2046-2t)
    }
    const int bin0 = BINS2 - 1 - 2 * tid;
    const int bin1 = bin0 - 1;
    float s0 = (float)c0 * bin_center(bin0);
    float s1 = (float)c1 * bin_center(bin1);
    unsigned tc = c0 + c1; float ts = s0 + s1;

    // two-level inclusive scan over (tc, ts) in rank order (16 waves)
    unsigned lane = tid & 63, w = tid >> 6;
    unsigned ic = tc; float is = ts;
    #pragma unroll
    for (int off = 1; off < 64; off <<= 1) {
        unsigned uc = __shfl_up(ic, off);
        float    us = __shfl_up(is, off);
        if (lane >= off) { ic += uc; is += us; }
    }
    if (lane == 63) { wtc[w] = ic; wts[w] = is; }
    __syncthreads();
    unsigned woc = 0; float wos = 0.f;
    for (unsigned i = 0; i < w; ++i) { woc += wtc[i]; wos += wts[i]; }
    unsigned before_c = woc + ic - tc;   // count strictly above my first rank
    float    before_s = wos + is - ts;

    const unsigned n_pos = s_npos;
    const float pos_sum = s_psum;
    const unsigned n_neg = NPIX - n_pos;
    const float pos_part = (n_pos > 0u) ? pos_sum / (float)n_pos : 0.f;
    if (n_neg == 0u) {
        if (tid == 0) atomicAdd(out, (pos_part - 1.f) / (float)NSAMP); // sentinel -1
        return;
    }
    unsigned k;
    if (n_pos > 0u) {
        k = 3u * n_pos;
        if (k > n_neg) k = n_neg;
        if (k < 1u) k = 1u;
    } else {
        k = 500u;   // fallback: top-500 (all pixels are negatives when n_pos==0)
    }

    if (before_c < k && before_c + c0 >= k) {
        unsigned kpp = k - before_c;
        float topk = before_s + (float)kpp * bin_center(bin0);
        atomicAdd(out, (pos_part + topk / (float)k) / (float)NSAMP);
    }
    before_c += c0; before_s += s0;
    if (before_c < k && before_c + c1 >= k) {
        unsigned kpp = k - before_c;
        float topk = before_s + (float)kpp * bin_center(bin1);
        atomicAdd(out, (pos_part + topk / (float)k) / (float)NSAMP);
    }
}

extern "C" void kernel_launch(void* const* d_in, const int* in_sizes, int n_in,
                              void* d_out, int out_size, void* d_ws, size_t ws_size,
                              hipStream_t stream)
{
    (void)in_sizes; (void)n_in; (void)out_size; (void)ws_size;
    const float* gt_r = (const float*)d_in[0];
    const float* gt_a = (const float*)d_in[1];
    const float* pr_r = (const float*)d_in[2];
    const float* pr_a = (const float*)d_in[3];
    const float* conf = (const float*)d_in[4];

    char* ws = (char*)d_ws;
    unsigned int*       part  = (unsigned int*)ws;
    unsigned long long* pstat = (unsigned long long*)(ws + PSTAT_OFF);

    dim3 gridH(BLKROW, NSAMP);
    k_hist<<<gridH, THREADS, 0, stream>>>(gt_r, gt_a, pr_r, pr_a, conf,
                                          part, pstat, (float*)d_out);
    k_sel<<<ROWS, SELTHREADS, 0, stream>>>(part, pstat, (float*)d_out);
}